// Round 4
// baseline (981.907 us; speedup 1.0000x reference)
//
#include <hip/hip_runtime.h>

#define LSTM_B 4096
#define LSTM_S 512
#define LSTM_H 50

__device__ __forceinline__ float fast_sigmoid(float v) {
    return 1.0f / (1.0f + __expf(-v));
}
// robust tanh via exp: saturates correctly for large |v|
__device__ __forceinline__ float fast_tanh(float v) {
    return 1.0f - 2.0f / (__expf(2.0f * v) + 1.0f);
}

// One wave per TWO batch elements. Lane j<50 owns hidden unit j for both:
// W_hh rows j,50+j,100+j,150+j are held register-resident (asm keep-alive
// makes the loaded values opaque so the compiler cannot re-load them from
// global each step — rounds 1/2 did exactly that, VGPR_Count=120, ~950us).
// Two batches per wave amortize the weights and give 8 independent FMA
// chains for in-wave latency hiding at 1-wave/SIMD occupancy.
__global__ __launch_bounds__(64, 1) void lstm_fused_kernel(
    const float* __restrict__ x,      // [B, S] (I==1)
    const float* __restrict__ W_ih,   // [200, 1]
    const float* __restrict__ W_hh,   // [200, 50]
    const float* __restrict__ b_ih,   // [200]
    const float* __restrict__ b_hh,   // [200]
    const float* __restrict__ W_fc,   // [1, 50]
    const float* __restrict__ b_fc,   // [1]
    float* __restrict__ out)          // [B]
{
    const int b0 = blockIdx.x * 2;
    const int b1 = b0 + 1;
    const int j = threadIdx.x;                    // 0..63
    const int jc = (j < LSTM_H) ? j : 0;          // clamp idle lanes in-bounds

    __shared__ __align__(16) float x_lds[2][LSTM_S];
    // double-buffered h per batch; stride 52 floats keeps float4 alignment
    __shared__ __align__(16) float h_lds[2][2][52];   // [buf][batch][unit]

    // stage x rows for both batches, coalesced float4
    {
        const float4* xg0 = reinterpret_cast<const float4*>(x + (size_t)b0 * LSTM_S);
        const float4* xg1 = reinterpret_cast<const float4*>(x + (size_t)b1 * LSTM_S);
        float4* xs0 = reinterpret_cast<float4*>(x_lds[0]);
        float4* xs1 = reinterpret_cast<float4*>(x_lds[1]);
        xs0[j] = xg0[j]; xs0[j + 64] = xg0[j + 64];
        xs1[j] = xg1[j]; xs1[j + 64] = xg1[j + 64];
    }
    if (j < LSTM_H) { h_lds[0][0][j] = 0.0f; h_lds[0][1][j] = 0.0f; }

    // per-lane weights: 4 gate rows of W_hh → registers
    float w[4][LSTM_H];
    float wih[4], bias[4];
    #pragma unroll
    for (int g = 0; g < 4; ++g) {
        const int row = g * LSTM_H + jc;
        const float* wr = W_hh + row * LSTM_H;
        #pragma unroll
        for (int k = 0; k < LSTM_H; ++k) w[g][k] = wr[k];
        wih[g]  = W_ih[row];                      // I == 1
        bias[g] = b_ih[row] + b_hh[row];
    }
    // Opaque keep-alive: compiler cannot rematerialize these from memory,
    // so they stay in VGPRs for the whole step loop.
    #pragma unroll
    for (int g = 0; g < 4; ++g) {
        asm volatile("" : "+v"(wih[g]), "+v"(bias[g]));
        #pragma unroll
        for (int k = 0; k < LSTM_H; ++k) asm volatile("" : "+v"(w[g][k]));
    }

    float c0 = 0.0f, c1 = 0.0f, h0j = 0.0f, h1j = 0.0f;

    __syncthreads();

#define ACC1(z, hvc, g, kidx) z = fmaf(hvc, w[g][kidx], z)
#define ACC4(zi, zf, zg, zo, hv, k0)                                          \
    ACC1(zi, hv.x, 0, k0+0); ACC1(zi, hv.y, 0, k0+1);                         \
    ACC1(zi, hv.z, 0, k0+2); ACC1(zi, hv.w, 0, k0+3);                         \
    ACC1(zf, hv.x, 1, k0+0); ACC1(zf, hv.y, 1, k0+1);                         \
    ACC1(zf, hv.z, 1, k0+2); ACC1(zf, hv.w, 1, k0+3);                         \
    ACC1(zg, hv.x, 2, k0+0); ACC1(zg, hv.y, 2, k0+1);                         \
    ACC1(zg, hv.z, 2, k0+2); ACC1(zg, hv.w, 2, k0+3);                         \
    ACC1(zo, hv.x, 3, k0+0); ACC1(zo, hv.y, 3, k0+1);                         \
    ACC1(zo, hv.z, 3, k0+2); ACC1(zo, hv.w, 3, k0+3)
#define ACCTAIL(zi, zf, zg, zo, hA, hB)                                       \
    ACC1(zi, hA, 0, 48); ACC1(zi, hB, 0, 49);                                 \
    ACC1(zf, hA, 1, 48); ACC1(zf, hB, 1, 49);                                 \
    ACC1(zg, hA, 2, 48); ACC1(zg, hB, 2, 49);                                 \
    ACC1(zo, hA, 3, 48); ACC1(zo, hB, 3, 49)

    for (int s = 0; s < LSTM_S; ++s) {
        const int buf = s & 1;
        const float* hc0 = h_lds[buf][0];
        const float* hc1 = h_lds[buf][1];
        const float4* h40 = reinterpret_cast<const float4*>(hc0);
        const float4* h41 = reinterpret_cast<const float4*>(hc1);

        const float xs0 = x_lds[0][s];
        const float xs1 = x_lds[1][s];
        float zi0 = fmaf(xs0, wih[0], bias[0]);
        float zf0 = fmaf(xs0, wih[1], bias[1]);
        float zg0 = fmaf(xs0, wih[2], bias[2]);
        float zo0 = fmaf(xs0, wih[3], bias[3]);
        float zi1 = fmaf(xs1, wih[0], bias[0]);
        float zf1 = fmaf(xs1, wih[1], bias[1]);
        float zg1 = fmaf(xs1, wih[2], bias[2]);
        float zo1 = fmaf(xs1, wih[3], bias[3]);

        #pragma unroll
        for (int kk = 0; kk < 12; ++kk) {         // k = 0..47 via float4 broadcast
            const float4 hv0 = h40[kk];
            const float4 hv1 = h41[kk];
            const int k0 = 4 * kk;
            ACC4(zi0, zf0, zg0, zo0, hv0, k0);
            ACC4(zi1, zf1, zg1, zo1, hv1, k0);
        }
        {                                         // tail k = 48, 49
            const float a0 = hc0[48], a1 = hc0[49];
            const float d0 = hc1[48], d1 = hc1[49];
            ACCTAIL(zi0, zf0, zg0, zo0, a0, a1);
            ACCTAIL(zi1, zf1, zg1, zo1, d0, d1);
        }

        {
            const float ig = fast_sigmoid(zi0);
            const float fg = fast_sigmoid(zf0);
            const float gg = fast_tanh(zg0);
            const float og = fast_sigmoid(zo0);
            c0  = fmaf(fg, c0, ig * gg);
            h0j = og * fast_tanh(c0);
        }
        {
            const float ig = fast_sigmoid(zi1);
            const float fg = fast_sigmoid(zf1);
            const float gg = fast_tanh(zg1);
            const float og = fast_sigmoid(zo1);
            c1  = fmaf(fg, c1, ig * gg);
            h1j = og * fast_tanh(c1);
        }

        if (j < LSTM_H) {
            h_lds[buf ^ 1][0][j] = h0j;
            h_lds[buf ^ 1][1][j] = h1j;
        }
        __syncthreads();                          // single-wave block: cheap
    }

    // out[b] = sigmoid(h_last . W_fc + b_fc), wave-wide shfl reductions
    const float wfc = (j < LSTM_H) ? W_fc[jc] : 0.0f;
    float r0 = (j < LSTM_H) ? (wfc * h0j) : 0.0f;
    float r1 = (j < LSTM_H) ? (wfc * h1j) : 0.0f;
    #pragma unroll
    for (int off = 32; off > 0; off >>= 1) {
        r0 += __shfl_down(r0, off);
        r1 += __shfl_down(r1, off);
    }
    if (j == 0) {
        const float bfc = b_fc[0];
        out[b0] = fast_sigmoid(r0 + bfc);
        out[b1] = fast_sigmoid(r1 + bfc);
    }
}

extern "C" void kernel_launch(void* const* d_in, const int* in_sizes, int n_in,
                              void* d_out, int out_size, void* d_ws, size_t ws_size,
                              hipStream_t stream) {
    const float* x    = (const float*)d_in[0];
    const float* W_ih = (const float*)d_in[1];
    const float* W_hh = (const float*)d_in[2];
    const float* b_ih = (const float*)d_in[3];
    const float* b_hh = (const float*)d_in[4];
    const float* W_fc = (const float*)d_in[5];
    const float* b_fc = (const float*)d_in[6];
    float* out = (float*)d_out;

    lstm_fused_kernel<<<LSTM_B / 2, 64, 0, stream>>>(x, W_ih, W_hh, b_ih, b_hh,
                                                     W_fc, b_fc, out);
}

// Round 5
// 794.133 us; speedup vs baseline: 1.2365x; 1.2365x over previous
//
#include <hip/hip_runtime.h>

#define LSTM_B 4096
#define LSTM_S 512
#define LSTM_H 50
#define NPAIR 25   // 50 halfs = 25 half2 pairs

typedef _Float16 h2_t __attribute__((ext_vector_type(2)));

// D = S0.h[0]*S1.h[0] + S0.h[1]*S1.h[1] + S2  (f16 mul, f32 accumulate)
__device__ __forceinline__ float dot2(unsigned int hw, unsigned int ww, float acc) {
#if defined(__HIP_DEVICE_COMPILE__) && __has_builtin(__builtin_amdgcn_fdot2)
    return __builtin_amdgcn_fdot2(__builtin_bit_cast(h2_t, hw),
                                  __builtin_bit_cast(h2_t, ww), acc, false);
#else
    asm("v_dot2_f32_f16 %0, %1, %2, %0" : "+v"(acc) : "v"(hw), "v"(ww));
    return acc;
#endif
}

__device__ __forceinline__ float fast_sigmoid(float v) {
    return 1.0f / (1.0f + __expf(-v));
}
__device__ __forceinline__ float fast_tanh(float v) {
    return 1.0f - 2.0f / (__expf(2.0f * v) + 1.0f);
}

// One wave per batch element; lane j<50 owns hidden unit j (gate rows j,
// 50+j, 100+j, 150+j). Weights held as PACKED f16 pairs: 100 VGPRs for all
// 200 weights — fits inside the allocator's ~128-VGPR budget, which rounds
// 1-4 proved it will not exceed (it spilled/remat'ed 200 f32 weights at
// VGPR_Count=124, ~980us). v_dot2_f32_f16 also halves FMA issue count:
// 100 dot2/step instead of 200 fma. h is staged in LDS as f16 and read as
// broadcast uint4s (conflict-free), double-buffered, one barrier/step.
__global__ __launch_bounds__(64, 2) void lstm_fused_kernel(
    const float* __restrict__ x,      // [B, S] (I==1)
    const float* __restrict__ W_ih,   // [200, 1]
    const float* __restrict__ W_hh,   // [200, 50]
    const float* __restrict__ b_ih,   // [200]
    const float* __restrict__ b_hh,   // [200]
    const float* __restrict__ W_fc,   // [1, 50]
    const float* __restrict__ b_fc,   // [1]
    float* __restrict__ out)          // [B]
{
    const int b = blockIdx.x;
    const int j = threadIdx.x;                    // 0..63
    const int jc = (j < LSTM_H) ? j : 0;          // clamp idle lanes in-bounds

    __shared__ __align__(16) float    x_lds[LSTM_S];
    // 56 halfs per buffer = 112B = 7 uint4 rows; halfs 50..55 are padding
    __shared__ __align__(16) _Float16 h_lds[2][56];

    // stage x[b,:] into LDS, coalesced float4 (512 floats = 128 float4)
    {
        const float4* xg = reinterpret_cast<const float4*>(x + (size_t)b * LSTM_S);
        float4* xs = reinterpret_cast<float4*>(x_lds);
        xs[j]      = xg[j];
        xs[j + 64] = xg[j + 64];
    }
    if (j < LSTM_H) h_lds[0][j] = (_Float16)0.0f; // h0 = 0
    if (j < 6) {                                  // zero the pad halfs once
        h_lds[0][LSTM_H + j] = (_Float16)0.0f;
        h_lds[1][LSTM_H + j] = (_Float16)0.0f;
    }

    // per-lane weights: 4 gate rows of W_hh packed to f16 pairs (RNE cast)
    unsigned int wu[4][NPAIR];
    float wih[4], bias[4];
    #pragma unroll
    for (int g = 0; g < 4; ++g) {
        const int row = g * LSTM_H + jc;
        const float* wr = W_hh + row * LSTM_H;
        #pragma unroll
        for (int p = 0; p < NPAIR; ++p) {
            h2_t t;
            t.x = (_Float16)wr[2 * p];
            t.y = (_Float16)wr[2 * p + 1];
            wu[g][p] = __builtin_bit_cast(unsigned int, t);
        }
        wih[g]  = W_ih[row];                      // I == 1, keep f32
        bias[g] = b_ih[row] + b_hh[row];
    }
    // keep-alive: forbid re-deriving the packed weights from memory
    #pragma unroll
    for (int g = 0; g < 4; ++g) {
        asm volatile("" : "+v"(wih[g]), "+v"(bias[g]));
        #pragma unroll
        for (int p = 0; p < NPAIR; ++p) asm volatile("" : "+v"(wu[g][p]));
    }

    float c  = 0.0f;
    float hj = 0.0f;

    __syncthreads();

    for (int s = 0; s < LSTM_S; ++s) {
        const int buf = s & 1;
        const uint4* hcv = reinterpret_cast<const uint4*>(h_lds[buf]);

        const float xs = x_lds[s];
        float zi = fmaf(xs, wih[0], bias[0]);
        float zf = fmaf(xs, wih[1], bias[1]);
        float zg = fmaf(xs, wih[2], bias[2]);
        float zo = fmaf(xs, wih[3], bias[3]);

        // 25 half2 pairs of h(s-1), broadcast uint4 reads (no conflicts)
        #pragma unroll
        for (int t = 0; t < 7; ++t) {
            const uint4 q = hcv[t];
            const unsigned int qq[4] = {q.x, q.y, q.z, q.w};
            #pragma unroll
            for (int u = 0; u < 4; ++u) {
                const int p = 4 * t + u;
                if (p < NPAIR) {
                    zi = dot2(qq[u], wu[0][p], zi);
                    zf = dot2(qq[u], wu[1][p], zf);
                    zg = dot2(qq[u], wu[2][p], zg);
                    zo = dot2(qq[u], wu[3][p], zo);
                }
            }
        }

        const float ig = fast_sigmoid(zi);
        const float fg = fast_sigmoid(zf);
        const float gg = fast_tanh(zg);
        const float og = fast_sigmoid(zo);
        c  = fmaf(fg, c, ig * gg);
        hj = og * fast_tanh(c);

        if (j < LSTM_H) h_lds[buf ^ 1][j] = (_Float16)hj;
        __syncthreads();                          // single-wave block: cheap
    }

    // out[b] = sigmoid(h_last . W_fc + b_fc), wave-wide shfl reduction
    float contrib = (j < LSTM_H) ? (W_fc[jc] * hj) : 0.0f;
    #pragma unroll
    for (int off = 32; off > 0; off >>= 1)
        contrib += __shfl_down(contrib, off);
    if (j == 0) out[b] = fast_sigmoid(contrib + b_fc[0]);
}

extern "C" void kernel_launch(void* const* d_in, const int* in_sizes, int n_in,
                              void* d_out, int out_size, void* d_ws, size_t ws_size,
                              hipStream_t stream) {
    const float* x    = (const float*)d_in[0];
    const float* W_ih = (const float*)d_in[1];
    const float* W_hh = (const float*)d_in[2];
    const float* b_ih = (const float*)d_in[3];
    const float* b_hh = (const float*)d_in[4];
    const float* W_fc = (const float*)d_in[5];
    const float* b_fc = (const float*)d_in[6];
    float* out = (float*)d_out;

    lstm_fused_kernel<<<LSTM_B, 64, 0, stream>>>(x, W_ih, W_hh, b_ih, b_hh,
                                                 W_fc, b_fc, out);
}